// Round 11
// baseline (144.007 us; speedup 1.0000x reference)
//
#include <hip/hip_runtime.h>

// Problem constants (compile-time, from reference):
//   B=2, D=H=W=160, C=2, N_LABELS=25, MAX_LABEL=48
//   voxels/batch V = 160^3 = 4,096,000 ; total voxels = 8,192,000
#define VPB   4096000
#define NLAB  25
#define TOTAL_VOX 8192000

// GEN_LABELS = {0,2,3,4,5,7,8,10,11,12,13,14,15,16,17,18,24,26,28,41,42,43,44,46,47}
// encoded as a 48-bit mask; row(label) = popcount(mask & ((1<<label)-1)).
#define GEN_MASK 0x0000DE001507FDBDull

// Round-13: persistent waves + software pipeline. r12 (128t blocks) gave a
// small real gain (41.5->40.3) but occupancy FELL (67->63): slot-refill
// theory dead. Residual theory: load DUTY CYCLE — one-shot waves keep loads
// outstanding only during their brief load window (issue 2 loads, wait,
// compute, store, die; ~8K-cycle lifetime for a 3-VMEM body). This kernel
// keeps 16K waves resident for the whole dispatch, each running 8 pipelined
// iterations: loads for iter i+1 are in flight during compute+store of
// iter i -> outstanding-loads duty cycle ~100%, contiguous 12 MB slabs,
// zero wave churn. Distinct from r11's failed burst-depth test (4 chunks
// 8 MB apart, loads drained once).
//   2000 blocks x 256 t x 2 vox x 8 iter = 8,192,000 voxels exactly.
//   Iter slab = 1,024,000 vox; batch boundary = 4 slabs (compile-time select).
// Round-3 lesson kept: NO nontemporal stores (1.74x WRITE_SIZE amplification).
#define NBLK    2000
#define TPB     256
#define THREADS (NBLK * TPB)            // 512,000
#define SLABV   (THREADS * 2)           // 1,024,000 voxels per iteration
#define NITER   8

__global__ __launch_bounds__(256) void gmm_sample_kernel(
    const int*   __restrict__ labels,   // [B*V] (trailing dim 1 squeezed)
    const float* __restrict__ means,    // [B, 25, 2]
    const float* __restrict__ stds,     // [B, 25, 2]
    const float* __restrict__ noise,    // [B*V, 2]
    float*       __restrict__ out)      // [B*V, 2]
{
    const int tid  = threadIdx.x;
    const int g    = blockIdx.x * TPB + tid;    // < 512,000
    const int lane = tid & 63;

    // per-lane register table: lane l holds entries for label VALUE l (0..47)
    int row = (int)__popcll(GEN_MASK & ((1ull << lane) - 1ull));
    row = row < NLAB ? row : NLAB - 1;          // lanes 48-63: clamp (unused)

    // Both batches' table entries, loaded once (L1-hot 800 B total).
    const float2 m0 = *(const float2*)(means + (row << 1));
    const float2 s0 = *(const float2*)(stds  + (row << 1));
    const float2 m1 = *(const float2*)(means + ((NLAB + row) << 1));
    const float2 s1 = *(const float2*)(stds  + ((NLAB + row) << 1));

    // ---- software pipeline: prologue load for iter 0 ----
    const size_t base = (size_t)g << 1;
    int2   lab_cur = *(const int2*)  (labels + base);
    float4 nz_cur  = *(const float4*)(noise + (base << 1));

#pragma unroll
    for (int i = 0; i < NITER; ++i) {
        // issue next-iteration loads BEFORE consuming current (stay in flight
        // under the shuffle+fma+store below)
        int2   lab_nxt;
        float4 nz_nxt;
        if (i < NITER - 1) {
            const size_t vn = (size_t)(i + 1) * SLABV + base;
            lab_nxt = *(const int2*)  (labels + vn);
            nz_nxt  = *(const float4*)(noise + (vn << 1));
        }

        // iterations 0-3 lie entirely in batch 0, 4-7 in batch 1
        // (slab = 1,024,000 vox; boundary = 4,096,000 = 4 slabs)
        const float2 m = (i >= 4) ? m1 : m0;
        const float2 s = (i >= 4) ? s1 : s0;

        const float e0x = __shfl(m.x, lab_cur.x, 64);
        const float e0y = __shfl(m.y, lab_cur.x, 64);
        const float e0z = __shfl(s.x, lab_cur.x, 64);
        const float e0w = __shfl(s.y, lab_cur.x, 64);
        const float e1x = __shfl(m.x, lab_cur.y, 64);
        const float e1y = __shfl(m.y, lab_cur.y, 64);
        const float e1z = __shfl(s.x, lab_cur.y, 64);
        const float e1w = __shfl(s.y, lab_cur.y, 64);

        float4 o;
        o.x = fmaf(e0z, nz_cur.x, e0x);
        o.y = fmaf(e0w, nz_cur.y, e0y);
        o.z = fmaf(e1z, nz_cur.z, e1x);
        o.w = fmaf(e1w, nz_cur.w, e1y);

        const size_t vc = (size_t)i * SLABV + base;
        *(float4*)(out + (vc << 1)) = o;

        lab_cur = lab_nxt;
        nz_cur  = nz_nxt;
    }
}

extern "C" void kernel_launch(void* const* d_in, const int* in_sizes, int n_in,
                              void* d_out, int out_size, void* d_ws, size_t ws_size,
                              hipStream_t stream) {
    const int*   labels = (const int*)  d_in[0];  // [2,160,160,160,1] int32
    const float* means  = (const float*)d_in[1];  // [2,25,2] f32
    const float* stds   = (const float*)d_in[2];  // [2,25,2] f32
    const float* noise  = (const float*)d_in[3];  // [2,160,160,160,2] f32
    float* out = (float*)d_out;                   // [2,160,160,160,2] f32

    // 2000 blocks x 256 threads, persistent across 8 pipelined iterations
    gmm_sample_kernel<<<NBLK, TPB, 0, stream>>>(labels, means, stds, noise, out);
}

// Round 12
// 140.143 us; speedup vs baseline: 1.0276x; 1.0276x over previous
//
#include <hip/hip_runtime.h>

// Problem constants (compile-time, from reference):
//   B=2, D=H=W=160, C=2, N_LABELS=25, MAX_LABEL=48
//   voxels/batch V = 160^3 = 4,096,000 ; total voxels = 8,192,000
#define VPB   4096000
#define NLAB  25
#define TOTAL_VOX 8192000

// GEN_LABELS = {0,2,3,4,5,7,8,10,11,12,13,14,15,16,17,18,24,26,28,41,42,43,44,46,47}
// encoded as a 48-bit mask; row(label) = popcount(mask & ((1<<label)-1)).
#define GEN_MASK 0x0000DE001507FDBDull

// Round-14: the LAST structural probe — 1 voxel/thread. Evidence across 7
// structures (16/8/8-pipe/8-persist/4/2/2 vox): perf is monotone in wave
// BREADTH, structure-independent, and every added per-wave depth regresses.
// The prior session stopped at 2-vox only to keep 8 B label loads (an
// assumption, never measured). This halves per-wave work once more:
// 1 dword + 1 dwordx2 load, 4 ds_bpermute, 1 dwordx2 store; 128K waves.
// Pre-committed: if this gains <3% (or regresses), the ~40 us plateau is the
// mixed-3-stream service floor (~4.1 TB/s effective) -> declare roofline.
// Round-3 lesson kept: NO nontemporal stores (1.74x WRITE_SIZE amplification).
__global__ __launch_bounds__(128) void gmm_sample_kernel(
    const int*   __restrict__ labels,   // [B*V] (trailing dim 1 squeezed)
    const float* __restrict__ means,    // [B, 25, 2]
    const float* __restrict__ stds,     // [B, 25, 2]
    const float* __restrict__ noise,    // [B*V, 2]
    float*       __restrict__ out)      // [B*V, 2]
{
    const int tid = threadIdx.x;
    const int g   = blockIdx.x * 128 + tid;     // voxel id, < 8,192,000

    // ---- streaming loads issue first, in flight during table load ----
    const int    lab = labels[g];
    const float2 nz  = *(const float2*)(noise + ((size_t)g << 1));

    // ---- per-lane register table: lane l holds (m0,m1,s0,s1) for label
    //      VALUE l (l in 0..47; input labels are always in GEN_LABELS) ----
    const int lane = tid & 63;
    int row = (int)__popcll(GEN_MASK & ((1ull << lane) - 1ull));
    row = row < NLAB ? row : NLAB - 1;          // lanes 48-63: clamp (data unused)

    // Batch boundary (4,096,000) = 32000 blocks * 128 exactly -> whole block
    // lies in one batch.
    const int boff = (g >= VPB) ? NLAB : 0;
    const float2 m = *(const float2*)(means + ((boff + row) << 1));  // L1-hot 400 B
    const float2 s = *(const float2*)(stds  + ((boff + row) << 1));

    // ---- gather = intra-wave shuffle (ds_bpermute), conflict-free ----
    const float emx = __shfl(m.x, lab, 64);
    const float emy = __shfl(m.y, lab, 64);
    const float esx = __shfl(s.x, lab, 64);
    const float esy = __shfl(s.y, lab, 64);

    float2 o;
    o.x = fmaf(esx, nz.x, emx);
    o.y = fmaf(esy, nz.y, emy);

    *(float2*)(out + ((size_t)g << 1)) = o;
}

extern "C" void kernel_launch(void* const* d_in, const int* in_sizes, int n_in,
                              void* d_out, int out_size, void* d_ws, size_t ws_size,
                              hipStream_t stream) {
    const int*   labels = (const int*)  d_in[0];  // [2,160,160,160,1] int32
    const float* means  = (const float*)d_in[1];  // [2,25,2] f32
    const float* stds   = (const float*)d_in[2];  // [2,25,2] f32
    const float* noise  = (const float*)d_in[3];  // [2,160,160,160,2] f32
    float* out = (float*)d_out;                   // [2,160,160,160,2] f32

    const int threads = 128;
    const int blocks  = TOTAL_VOX / threads;      // 64000
    gmm_sample_kernel<<<blocks, threads, 0, stream>>>(labels, means, stds, noise, out);
}